// Round 1
// baseline (3354.749 us; speedup 1.0000x reference)
//
#include <hip/hip_runtime.h>

#define TT 512
#define HH 1024
#define NC 8192   // 2 dirs * 4 gates * 1024 units

// ---- ws layout (in float units) ----
// [0, 4096)       h_buf[2 parity][2 dir][1024]
// [4096, 5120)    cnt: int[2 dir][512]
// [5120, +512K)   emb[512][1024]
// [WS_GX, +4M)    Gx[512][8192]
#define WS_HBUF 0
#define WS_CNT  4096
#define WS_EMB  5120
#define WS_GX   (5120 + TT * HH)

__device__ __forceinline__ float rdlane(float v, int l) {
  return __int_as_float(__builtin_amdgcn_readlane(__float_as_int(v), l));
}

// ---------------- Phase 1a: embedding gather ----------------
__global__ __launch_bounds__(256) void k_embed(const int* __restrict__ tok,
                                               const float* __restrict__ E,
                                               const float* __restrict__ be,
                                               float* __restrict__ emb) {
  int i = blockIdx.x * 256 + threadIdx.x;
  int t = i >> 10, h = i & (HH - 1);
  emb[i] = E[(size_t)tok[t] * HH + h] + be[h];
}

// ---------------- Phase 1b: input projection GEMM ----------------
// Gx[t][c] = sum_i emb[t][i] * W_d[g][i][u] + b_d[g][u]
// c = d*4096 + bp*64 + l,  u = bp*16 + (l>>2), g = l&3   (scan-lane order)
// tile: 128 t-rows x 64 c-cols; grid = (128 c-tiles, 4 t-tiles); 256 threads
__global__ __launch_bounds__(256) void k_gemm(const float* __restrict__ emb,
                                              const float* __restrict__ Wr,
                                              const float* __restrict__ Wl,
                                              const float* __restrict__ br,
                                              const float* __restrict__ bl,
                                              float* __restrict__ Gx) {
  __shared__ float As[32][132];  // [k][t]  (132: 16B-aligned rows, bank-spread)
  __shared__ float Bs[32][68];   // [k][c]
  int ct = blockIdx.x, ttile = blockIdx.y;
  int tid = threadIdx.x;
  int d = ct >> 6;
  int bp = ct & 63;
  int u0 = bp << 4;
  const float* W = d ? Wl : Wr;
  const float* bias = d ? bl : br;
  int t0 = ttile * 128;
  int tc = tid & 15, tr = tid >> 4;

  float acc[8][4];
#pragma unroll
  for (int i = 0; i < 8; ++i)
#pragma unroll
    for (int j = 0; j < 4; ++j) acc[i][j] = 0.f;

  int sk = tid & 31, st = tid >> 5;   // A staging: k = sk, t = st + 8*pass
  int sc = tid & 63, skb = tid >> 6;  // B staging: c = sc, k = skb + 4*pass
  int sg = sc & 3, su = u0 + (sc >> 2);

  for (int k0 = 0; k0 < HH; k0 += 32) {
    __syncthreads();
#pragma unroll
    for (int pass = 0; pass < 16; ++pass) {
      int t = st + (pass << 3);
      As[sk][t] = emb[(size_t)(t0 + t) * HH + k0 + sk];
    }
#pragma unroll
    for (int pass = 0; pass < 8; ++pass) {
      int k = skb + (pass << 2);
      Bs[k][sc] = W[((size_t)sg * 2048 + k0 + k) * HH + su];
    }
    __syncthreads();
#pragma unroll
    for (int k = 0; k < 32; ++k) {
      float4 bv = *(const float4*)&Bs[k][tc << 2];
      float4 a0 = *(const float4*)&As[k][tr << 3];
      float4 a1 = *(const float4*)&As[k][(tr << 3) + 4];
      float av[8] = {a0.x, a0.y, a0.z, a0.w, a1.x, a1.y, a1.z, a1.w};
#pragma unroll
      for (int i = 0; i < 8; ++i) {
        acc[i][0] = fmaf(av[i], bv.x, acc[i][0]);
        acc[i][1] = fmaf(av[i], bv.y, acc[i][1]);
        acc[i][2] = fmaf(av[i], bv.z, acc[i][2]);
        acc[i][3] = fmaf(av[i], bv.w, acc[i][3]);
      }
    }
  }
  int c0 = ct << 6;
  float b0 = bias[0 * HH + u0 + tc];
  float b1 = bias[1 * HH + u0 + tc];
  float b2 = bias[2 * HH + u0 + tc];
  float b3 = bias[3 * HH + u0 + tc];
#pragma unroll
  for (int i = 0; i < 8; ++i) {
    int t = t0 + (tr << 3) + i;
    float4 o;
    o.x = acc[i][0] + b0;
    o.y = acc[i][1] + b1;
    o.z = acc[i][2] + b2;
    o.w = acc[i][3] + b3;
    *(float4*)&Gx[(size_t)t * NC + c0 + (tc << 2)] = o;
  }
}

// ---------------- Phase 2: persistent bidirectional LSTM scan ----------------
// 128 blocks (64 fwd, 64 bwd) x 1024 threads (16 waves).
// Block owns 16 hidden units (64 gate-outputs = lane dim). Wave w owns
// h-slice i in [64w, 64w+64). Recurrent weights live in registers (64/lane).
__global__ __launch_bounds__(1024, 1) void k_scan(const float* __restrict__ Wr,
                                                  const float* __restrict__ Wl,
                                                  const float* __restrict__ Gx,
                                                  float* __restrict__ hbuf,
                                                  int* __restrict__ cnt,
                                                  float* __restrict__ out) {
  int b = blockIdx.x;
  int d = b >> 6, bp = b & 63;
  int tid = threadIdx.x;
  int w = tid >> 6, l = tid & 63;
  int u0 = bp << 4;
  int g = l & 3, ur = l >> 2;
  const float* W = d ? Wl : Wr;

  // one-time register load of recurrent weights: W_d[g][1024 + i][u]
  float wreg[64];
  {
    const float* wb = W + ((size_t)g * 2048 + HH + (w << 6)) * HH + (u0 + ur);
#pragma unroll
    for (int j = 0; j < 64; ++j) wreg[j] = wb[(size_t)j * HH];
  }

  __shared__ float red[16][64];
  float c_reg = 0.f;
  float* hb = hbuf + (d << 10);                 // + parity*2048
  int* mycnt = cnt + (d << 9);
  const float* gxbase = Gx + (d << 12) + (bp << 6);

  for (int t = 0; t < TT; ++t) {
    int p = t & 1;
    // coalesced 64-float slice of h for this wave
    float hv = hb[(p << 11) + (w << 6) + l];
    float acc0 = 0.f, acc1 = 0.f;
#pragma unroll
    for (int j = 0; j < 64; j += 2) {
      acc0 = fmaf(rdlane(hv, j), wreg[j], acc0);
      acc1 = fmaf(rdlane(hv, j + 1), wreg[j + 1], acc1);
    }
    red[w][l] = acc0 + acc1;
    __syncthreads();

    if (w == 0) {
      int rt = d ? (TT - 1 - t) : t;      // backward consumes reversed sequence
      float s = gxbase[(size_t)rt * NC + l];
#pragma unroll
      for (int ww = 0; ww < 16; ++ww) s += red[ww][l];
      int lb = l & ~3;
      float gi = __shfl(s, lb + 0);
      float go = __shfl(s, lb + 1);
      float gf = __shfl(s, lb + 2);
      float gc = __shfl(s, lb + 3);
      float ig = 1.f / (1.f + expf(-gi));
      float og = 1.f / (1.f + expf(-go));
      float fg = 1.f / (1.f + expf(-gf));
      float cg = tanhf(gc);
      c_reg = fg * c_reg + ig * cg;
      float hval = og * tanhf(c_reg);
      if (g == 0) {
        int uu = u0 + ur;
        hb[((p ^ 1) << 11) + uu] = hval;                    // recurrence
        out[(size_t)t * 2048 + (d << 10) + uu] = hval;      // annotations
        if (d == 0 && t == TT - 1) {
          out[(size_t)TT * 2048 + uu] = hval;               // h_f
          out[(size_t)TT * 2048 + HH + uu] = c_reg;         // c_f
        }
      }
    }

    if (t < TT - 1) {
      if (tid == 0) {
        __builtin_amdgcn_fence(__ATOMIC_RELEASE, "agent");
        __hip_atomic_fetch_add(&mycnt[t], 1, __ATOMIC_RELAXED,
                               __HIP_MEMORY_SCOPE_AGENT);
        while (__hip_atomic_load(&mycnt[t], __ATOMIC_RELAXED,
                                 __HIP_MEMORY_SCOPE_AGENT) < 64) {
        }
        __builtin_amdgcn_fence(__ATOMIC_ACQUIRE, "agent");
      }
      __syncthreads();
    }
  }
}

extern "C" void kernel_launch(void* const* d_in, const int* in_sizes, int n_in,
                              void* d_out, int out_size, void* d_ws, size_t ws_size,
                              hipStream_t stream) {
  const int* tok = (const int*)d_in[0];
  const float* E = (const float*)d_in[1];
  const float* be = (const float*)d_in[2];
  const float* Wr = (const float*)d_in[3];
  const float* br = (const float*)d_in[4];
  const float* Wl = (const float*)d_in[5];
  const float* bl = (const float*)d_in[6];
  float* out = (float*)d_out;
  float* ws = (float*)d_ws;

  float* hbuf = ws + WS_HBUF;
  int* cnt = (int*)(ws + WS_CNT);
  float* emb = ws + WS_EMB;
  float* Gx = ws + WS_GX;

  // zero h_buf (16KB) + barrier counters (4KB); ws is poisoned 0xAA each call
  hipMemsetAsync(hbuf, 0, (size_t)(4096 + 1024) * 4, stream);

  k_embed<<<dim3(TT * HH / 256), dim3(256), 0, stream>>>(tok, E, be, emb);
  k_gemm<<<dim3(128, 4), dim3(256), 0, stream>>>(emb, Wr, Wl, br, bl, Gx);
  k_scan<<<dim3(128), dim3(1024), 0, stream>>>(Wr, Wl, Gx, hbuf, cnt, out);
}